// Round 1
// baseline (299.666 us; speedup 1.0000x reference)
//
#include <hip/hip_runtime.h>
#include <hip/hip_bf16.h>
#include <stdint.h>

typedef unsigned short u16;
typedef unsigned int u32;
typedef __attribute__((ext_vector_type(8))) short short8;
typedef __attribute__((ext_vector_type(4))) float f32x4;

#define LOG2E 1.44269504f

static __device__ __forceinline__ u16 f2bf(float f) {
    u32 x = __float_as_uint(f);
    u32 r = (x + 0x7FFFu + ((x >> 16) & 1u)) >> 16;
    return (u16)r;
}
static __device__ __forceinline__ float bf2f(u16 u) {
    return __uint_as_float(((u32)u) << 16);
}

static __device__ __forceinline__ void g2l16(const void* g, void* l) {
    __builtin_amdgcn_global_load_lds((const __attribute__((address_space(1))) void*)g,
                                     (__attribute__((address_space(3))) void*)l, 16, 0, 0);
}

// ---------------------------------------------------------------- convert
__global__ __launch_bounds__(256) void k_cvt(const float* __restrict__ in,
                                             u16* __restrict__ out, int n8) {
    int i = blockIdx.x * 256 + threadIdx.x;
    if (i >= n8) return;
    const float4* p = (const float4*)in + (size_t)i * 2;
    float4 a = p[0], b = p[1];
    short8 o;
    o[0] = f2bf(a.x); o[1] = f2bf(a.y); o[2] = f2bf(a.z); o[3] = f2bf(a.w);
    o[4] = f2bf(b.x); o[5] = f2bf(b.y); o[6] = f2bf(b.z); o[7] = f2bf(b.w);
    *((short8*)out + i) = o;
}

// ---------------------------------------------------------------- gates
__global__ __launch_bounds__(256) void k_gates(
    const float* __restrict__ qin, const float* __restrict__ Wdy2,
    const float* __restrict__ bdy2, const float* __restrict__ Wdy,
    const float* __restrict__ bdy, const float* __restrict__ star_s,
    const float* __restrict__ star_b, float* __restrict__ glf,
    float* __restrict__ ghf) {
    __shared__ __align__(16) u16 wl[2][12 * 768];
    for (int idx = threadIdx.x; idx < 9216; idx += 256) {
        wl[0][idx] = f2bf(Wdy2[idx]);
        wl[1][idx] = f2bf(Wdy[idx]);
    }
    __syncthreads();
    int w = threadIdx.x >> 6, lane = threadIdx.x & 63;
    float ss = star_s[0], sb = star_b[0];
    int t0 = blockIdx.x * 32 + w * 8;
    for (int tt = 0; tt < 8; ++tt) {
        int t = t0 + tt;
        float sr[12];
#pragma unroll
        for (int i = 0; i < 12; ++i) {
            float x = qin[(size_t)t * 768 + lane + 64 * i];
            x = fmaxf(x, 0.f);
            sr[i] = ss * x * x + sb;
        }
        float acc[24];
#pragma unroll
        for (int h = 0; h < 24; ++h) acc[h] = 0.f;
#pragma unroll
        for (int i = 0; i < 12; ++i) {
#pragma unroll
            for (int h = 0; h < 12; ++h) {
                acc[h]      += sr[i] * bf2f(wl[0][h * 768 + lane + 64 * i]);
                acc[12 + h] += sr[i] * bf2f(wl[1][h * 768 + lane + 64 * i]);
            }
        }
        float keep = 0.f;
#pragma unroll
        for (int h = 0; h < 24; ++h) {
            float v = acc[h];
#pragma unroll
            for (int msk = 1; msk < 64; msk <<= 1) v += __shfl_xor(v, msk);
            if (lane == h) keep = v;
        }
        if (lane < 12) {
            glf[(size_t)t * 12 + lane] = tanhf(keep + bdy2[lane]);
        } else if (lane < 24) {
            float x = keep + bdy[lane - 12];
            float sp = (x > 15.f) ? x : log1pf(expf(x));
            float d2 = sp * sp;
            ghf[(size_t)t * 12 + (lane - 12)] = 2.f * d2 / (d2 + 0.3678f);
        }
    }
}

// ---------------------------------------------------------------- GEMM core (A MxK bf16 row-major, W NxK bf16 row-major)
__device__ __forceinline__ void gemm_core(const u16* __restrict__ A,
                                          const u16* __restrict__ W, u16* As,
                                          u16* Bs, int rowA0, int rowB0,
                                          int lane, int w, int wm, int wn,
                                          f32x4 acc[4][4]) {
#pragma unroll
    for (int m = 0; m < 4; ++m)
#pragma unroll
        for (int n = 0; n < 4; ++n) acc[m][n] = (f32x4){0.f, 0.f, 0.f, 0.f};

    auto stage = [&](int buf, int k0) {
#pragma unroll
        for (int j = 0; j < 2; ++j) {
            int idx = w * 128 + j * 64 + lane;
            g2l16(A + (size_t)(rowA0 + (idx >> 2)) * 768 + k0 + (idx & 3) * 8,
                  As + buf * 4096 + (w * 128 + j * 64) * 8);
            g2l16(W + (size_t)(rowB0 + (idx >> 2)) * 768 + k0 + (idx & 3) * 8,
                  Bs + buf * 4096 + (w * 128 + j * 64) * 8);
        }
    };

    stage(0, 0);
    __syncthreads();
    int buf = 0;
    for (int t = 0; t < 24; ++t) {
        if (t < 23) stage(buf ^ 1, (t + 1) * 32);
        short8 a[4], b[4];
#pragma unroll
        for (int m = 0; m < 4; ++m)
            a[m] = *(const short8*)(As + buf * 4096 +
                                    (wm * 64 + m * 16 + (lane & 15)) * 32 +
                                    (lane >> 4) * 8);
#pragma unroll
        for (int n = 0; n < 4; ++n)
            b[n] = *(const short8*)(Bs + buf * 4096 +
                                    (wn * 64 + n * 16 + (lane & 15)) * 32 +
                                    (lane >> 4) * 8);
#pragma unroll
        for (int m = 0; m < 4; ++m)
#pragma unroll
            for (int n = 0; n < 4; ++n)
                acc[m][n] = __builtin_amdgcn_mfma_f32_16x16x32_bf16(
                    a[m], b[n], acc[m][n], 0, 0, 0);
        __syncthreads();
        buf ^= 1;
    }
}

// ---------------------------------------------------------------- QKV GEMM
__global__ __launch_bounds__(256, 2) void k_gemm_qkv(
    const u16* __restrict__ qbf, const u16* __restrict__ kvbf,
    const u16* __restrict__ Wqb, const u16* __restrict__ Wkb,
    const u16* __restrict__ Wvb, u16* __restrict__ Qb, u16* __restrict__ Kb,
    u16* __restrict__ VTb, u16* __restrict__ vlin) {
    __shared__ __align__(16) u16 smem[16384];
    u16* As = smem;
    u16* Bs = smem + 8192;
    int mode = blockIdx.z;
    const u16* A = (mode == 0) ? qbf : kvbf;
    const u16* W = (mode == 0) ? Wqb : (mode == 1 ? Wkb : Wvb);
    int bid = blockIdx.x;
    int tm = bid / 6, tn = bid % 6;
    int tid = threadIdx.x, lane = tid & 63, w = tid >> 6;
    int wm = w >> 1, wn = w & 1;
    int rowA0 = tm * 128, rowB0 = tn * 128;

    f32x4 acc[4][4];
    gemm_core(A, W, As, Bs, rowA0, rowB0, lane, w, wm, wn, acc);

    if (mode < 2) {
        u16* dst = (mode == 0) ? Qb : Kb;
#pragma unroll
        for (int m = 0; m < 4; ++m)
#pragma unroll
            for (int n = 0; n < 4; ++n)
#pragma unroll
                for (int r = 0; r < 4; ++r) {
                    int row = rowA0 + wm * 64 + m * 16 + (lane >> 4) * 4 + r;
                    int col = rowB0 + wn * 64 + n * 16 + (lane & 15);
                    int bb = row >> 10, nn = row & 1023, hh = col >> 6,
                        dd = col & 63;
                    dst[((size_t)(bb * 12 + hh) << 16) + (nn << 6) + dd] =
                        f2bf(acc[m][n][r]);
                }
    } else {
#pragma unroll
        for (int m = 0; m < 4; ++m)
#pragma unroll
            for (int n = 0; n < 4; ++n)
#pragma unroll
                for (int r = 0; r < 4; ++r) {
                    int row = rowA0 + wm * 64 + m * 16 + (lane >> 4) * 4 + r;
                    int col = rowB0 + wn * 64 + n * 16 + (lane & 15);
                    vlin[(size_t)row * 768 + col] = f2bf(acc[m][n][r]);
                }
        __syncthreads();
        // transpose C tile (128 tokens x 128 douts) through LDS -> VT (B,H,D,N)
#pragma unroll
        for (int m = 0; m < 4; ++m)
#pragma unroll
            for (int n = 0; n < 4; ++n)
#pragma unroll
                for (int r = 0; r < 4; ++r) {
                    int rl = wm * 64 + m * 16 + (lane >> 4) * 4 + r;
                    int cl = wn * 64 + n * 16 + (lane & 15);
                    smem[cl * 128 + rl] = f2bf(acc[m][n][r]);
                }
        __syncthreads();
        int bb = rowA0 >> 10, nn0 = rowA0 & 1023;
#pragma unroll
        for (int j = 0; j < 8; ++j) {
            int idx = j * 256 + tid;
            int rT = idx >> 4, cc = idx & 15;
            int dout = rowB0 + rT, hh = dout >> 6, dd = dout & 63;
            *(short8*)(VTb + ((size_t)(bb * 12 + hh) * 64 + dd) * 1024 + nn0 +
                       cc * 8) = *(const short8*)(smem + rT * 128 + cc * 8);
        }
    }
}

// ---------------------------------------------------------------- out GEMM
__global__ __launch_bounds__(256, 2) void k_gemm_out(
    const u16* __restrict__ xf, const u16* __restrict__ Wpb,
    const float* __restrict__ bp, float* __restrict__ out) {
    __shared__ __align__(16) u16 smem[16384];
    u16* As = smem;
    u16* Bs = smem + 8192;
    int bid = blockIdx.x;
    int tm = bid / 6, tn = bid % 6;
    int tid = threadIdx.x, lane = tid & 63, w = tid >> 6;
    int wm = w >> 1, wn = w & 1;
    int rowA0 = tm * 128, rowB0 = tn * 128;

    f32x4 acc[4][4];
    gemm_core(xf, Wpb, As, Bs, rowA0, rowB0, lane, w, wm, wn, acc);

#pragma unroll
    for (int m = 0; m < 4; ++m)
#pragma unroll
        for (int n = 0; n < 4; ++n)
#pragma unroll
            for (int r = 0; r < 4; ++r) {
                int row = rowA0 + wm * 64 + m * 16 + (lane >> 4) * 4 + r;
                int col = rowB0 + wn * 64 + n * 16 + (lane & 15);
                out[(size_t)row * 768 + col] = acc[m][n][r] + bp[col];
            }
}

// ---------------------------------------------------------------- attention
__global__ __launch_bounds__(256, 2) void k_attn(const u16* __restrict__ Qb,
                                                 const u16* __restrict__ Kb,
                                                 const u16* __restrict__ VTb,
                                                 u16* __restrict__ xattn) {
    __shared__ __align__(16) u16 Ks[2][2048];
    __shared__ __align__(16) u16 Vs[2][2048];
    __shared__ __align__(16) u16 Ps[4][512];
    int bh = blockIdx.y, b = bh / 12, h = bh % 12;
    int tid = threadIdx.x, lane = tid & 63, w = tid >> 6;
    int q0 = blockIdx.x * 64 + w * 16;
    const u16* Qp = Qb + ((size_t)bh << 16);
    const u16* Kp = Kb + ((size_t)bh << 16);
    const u16* Vp = VTb + ((size_t)bh << 16);

    short8 qf[2];
#pragma unroll
    for (int s = 0; s < 2; ++s)
        qf[s] = *(const short8*)(Qp + (size_t)(q0 + (lane & 15)) * 64 + s * 32 +
                                 (lane >> 4) * 8);

    f32x4 o[4];
#pragma unroll
    for (int n = 0; n < 4; ++n) o[n] = (f32x4){0.f, 0.f, 0.f, 0.f};
    float mr[4], lr[4];
#pragma unroll
    for (int r = 0; r < 4; ++r) { mr[r] = -1e30f; lr[r] = 0.f; }

    auto stage = [&](int buf, int kv0) {
        int idx = w * 64 + lane;
        g2l16(Kp + (size_t)(kv0 + (idx >> 3)) * 64 + (idx & 7) * 8,
              &Ks[buf][w * 512]);
        g2l16(Vp + (size_t)(idx >> 2) * 1024 + kv0 + (idx & 3) * 8,
              &Vs[buf][w * 512]);
    };

    stage(0, 0);
    __syncthreads();
    int buf = 0;
    const float SC = 0.125f * LOG2E;
    for (int t = 0; t < 32; ++t) {
        if (t < 31) stage(buf ^ 1, (t + 1) * 32);
        f32x4 s[2];
        s[0] = (f32x4){0.f, 0.f, 0.f, 0.f};
        s[1] = (f32x4){0.f, 0.f, 0.f, 0.f};
#pragma unroll
        for (int nf = 0; nf < 2; ++nf)
#pragma unroll
            for (int ks = 0; ks < 2; ++ks) {
                short8 kf = *(const short8*)&Ks[buf][(nf * 16 + (lane & 15)) * 64 +
                                                     ks * 32 + (lane >> 4) * 8];
                s[nf] = __builtin_amdgcn_mfma_f32_16x16x32_bf16(qf[ks], kf,
                                                                s[nf], 0, 0, 0);
            }
        float tmax[4];
#pragma unroll
        for (int r = 0; r < 4; ++r) {
            s[0][r] *= SC;
            s[1][r] *= SC;
            tmax[r] = fmaxf(s[0][r], s[1][r]);
        }
#pragma unroll
        for (int msk = 1; msk < 16; msk <<= 1)
#pragma unroll
            for (int r = 0; r < 4; ++r)
                tmax[r] = fmaxf(tmax[r], __shfl_xor(tmax[r], msk));
        float psum[4];
#pragma unroll
        for (int r = 0; r < 4; ++r) {
            float mnew = fmaxf(mr[r], tmax[r]);
            float sc_ = exp2f(mr[r] - mnew);
            mr[r] = mnew;
            s[0][r] = exp2f(s[0][r] - mnew);
            s[1][r] = exp2f(s[1][r] - mnew);
            psum[r] = s[0][r] + s[1][r];
            lr[r] = lr[r] * sc_;
#pragma unroll
            for (int n = 0; n < 4; ++n) o[n][r] *= sc_;
        }
#pragma unroll
        for (int msk = 1; msk < 16; msk <<= 1)
#pragma unroll
            for (int r = 0; r < 4; ++r) psum[r] += __shfl_xor(psum[r], msk);
#pragma unroll
        for (int r = 0; r < 4; ++r) lr[r] += psum[r];
        // P -> per-wave LDS (transpose to A-fragment layout)
#pragma unroll
        for (int nf = 0; nf < 2; ++nf)
#pragma unroll
            for (int r = 0; r < 4; ++r)
                Ps[w][((lane >> 4) * 4 + r) * 32 + nf * 16 + (lane & 15)] =
                    f2bf(s[nf][r]);
        short8 pa = *(const short8*)&Ps[w][(lane & 15) * 32 + (lane >> 4) * 8];
#pragma unroll
        for (int n = 0; n < 4; ++n) {
            short8 vf = *(const short8*)&Vs[buf][(n * 16 + (lane & 15)) * 32 +
                                                 (lane >> 4) * 8];
            o[n] = __builtin_amdgcn_mfma_f32_16x16x32_bf16(pa, vf, o[n], 0, 0, 0);
        }
        __syncthreads();
        buf ^= 1;
    }
#pragma unroll
    for (int r = 0; r < 4; ++r) lr[r] = 1.f / lr[r];
#pragma unroll
    for (int n = 0; n < 4; ++n)
#pragma unroll
        for (int r = 0; r < 4; ++r) {
            int q = q0 + (lane >> 4) * 4 + r;
            int d = n * 16 + (lane & 15);
            xattn[(size_t)(b * 1024 + q) * 768 + h * 64 + d] =
                f2bf(o[n][r] * lr[r]);
        }
}

// ---------------------------------------------------------------- combine
__global__ __launch_bounds__(256) void k_combine(
    const u16* __restrict__ xattn, const u16* __restrict__ vlin,
    const float* __restrict__ glf, const float* __restrict__ ghf,
    const float* __restrict__ lfg, const float* __restrict__ hfg,
    u16* __restrict__ xfinal) {
    int i = blockIdx.x * 256 + threadIdx.x;  // 8-elem group index
    size_t base = (size_t)i * 8;
    int c = (int)(base % 768);
    int t = (int)(base / 768);
    int h = c >> 6;
    float a_lf = glf[(size_t)t * 12 + h];
    float a_hf = ghf[(size_t)t * 12 + h];
    short8 xa8 = *((const short8*)xattn + i);
    short8 vl8 = *((const short8*)vlin + i);
    float4 lg0 = *(const float4*)(lfg + c);
    float4 lg1 = *(const float4*)(lfg + c + 4);
    float4 hg0 = *(const float4*)(hfg + c);
    float4 hg1 = *(const float4*)(hfg + c + 4);
    float lg[8] = {lg0.x, lg0.y, lg0.z, lg0.w, lg1.x, lg1.y, lg1.z, lg1.w};
    float hg[8] = {hg0.x, hg0.y, hg0.z, hg0.w, hg1.x, hg1.y, hg1.z, hg1.w};
    short8 o;
#pragma unroll
    for (int j = 0; j < 8; ++j) {
        float xa = bf2f((u16)xa8[j]);
        float v = bf2f((u16)vl8[j]);
        float val = xa + xa * a_lf * lg[j] + a_hf * (v - xa) * hg[j];
        o[j] = f2bf(val);
    }
    *((short8*)xfinal + i) = o;
}

// ---------------------------------------------------------------- launch
extern "C" void kernel_launch(void* const* d_in, const int* in_sizes, int n_in,
                              void* d_out, int out_size, void* d_ws,
                              size_t ws_size, hipStream_t stream) {
    const float* q_in = (const float*)d_in[0];
    const float* kv_in = (const float*)d_in[1];
    const float* Wq = (const float*)d_in[2];
    const float* Wk = (const float*)d_in[3];
    const float* Wv = (const float*)d_in[4];
    const float* Wp = (const float*)d_in[5];
    const float* bp = (const float*)d_in[6];
    const float* Wdy2 = (const float*)d_in[7];
    const float* bdy2 = (const float*)d_in[8];
    const float* Wdy = (const float*)d_in[9];
    const float* bdy = (const float*)d_in[10];
    const float* lfg = (const float*)d_in[11];
    const float* hfg = (const float*)d_in[12];
    const float* st_s = (const float*)d_in[13];
    const float* st_b = (const float*)d_in[14];
    float* out = (float*)d_out;

    char* ws = (char*)d_ws;
    const size_t MC2 = (size_t)8192 * 768 * 2;  // 12.58 MB
    const size_t WB = (size_t)768 * 768 * 2;    // 1.18 MB
    u16* qbf = (u16*)(ws);
    u16* kvbf = (u16*)(ws + MC2);
    u16* Wqb = (u16*)(ws + 2 * MC2);
    u16* Wkb = (u16*)(ws + 2 * MC2 + WB);
    u16* Wvb = (u16*)(ws + 2 * MC2 + 2 * WB);
    u16* Wpb = (u16*)(ws + 2 * MC2 + 3 * WB);
    u16* Qb = (u16*)(ws + 2 * MC2 + 4 * WB);
    u16* Kb = (u16*)(ws + 3 * MC2 + 4 * WB);
    u16* VTb = (u16*)(ws + 4 * MC2 + 4 * WB);
    u16* vlin = (u16*)(ws + 5 * MC2 + 4 * WB);
    float* glf = (float*)(ws + 6 * MC2 + 4 * WB);
    float* ghf = (float*)(ws + 6 * MC2 + 4 * WB + (size_t)8192 * 12 * 4);
    u16* xattn = kvbf;   // alias: kv_bf dead after QKV GEMM
    u16* xfinal = qbf;   // alias: q_bf dead after QKV GEMM

    k_cvt<<<3072, 256, 0, stream>>>(q_in, qbf, 786432);
    k_cvt<<<3072, 256, 0, stream>>>(kv_in, kvbf, 786432);
    k_cvt<<<288, 256, 0, stream>>>(Wq, Wqb, 73728);
    k_cvt<<<288, 256, 0, stream>>>(Wk, Wkb, 73728);
    k_cvt<<<288, 256, 0, stream>>>(Wv, Wvb, 73728);
    k_cvt<<<288, 256, 0, stream>>>(Wp, Wpb, 73728);
    k_gates<<<256, 256, 0, stream>>>(q_in, Wdy2, bdy2, Wdy, bdy, st_s, st_b,
                                     glf, ghf);
    k_gemm_qkv<<<dim3(384, 1, 3), 256, 0, stream>>>(qbf, kvbf, Wqb, Wkb, Wvb,
                                                    Qb, Kb, VTb, vlin);
    k_attn<<<dim3(16, 96), 256, 0, stream>>>(Qb, Kb, VTb, xattn);
    k_combine<<<3072, 256, 0, stream>>>(xattn, vlin, glf, ghf, lfg, hfg,
                                        xfinal);
    k_gemm_out<<<384, 256, 0, stream>>>(xfinal, Wpb, bp, out);
}

// Round 2
// 215.087 us; speedup vs baseline: 1.3932x; 1.3932x over previous
//
#include <hip/hip_runtime.h>
#include <hip/hip_bf16.h>
#include <stdint.h>

typedef unsigned short u16;
typedef unsigned int u32;
typedef __attribute__((ext_vector_type(8))) short short8;
typedef __attribute__((ext_vector_type(4))) float f32x4;

#define LOG2E 1.44269504f

static __device__ __forceinline__ u16 f2bf(float f) {
    u32 x = __float_as_uint(f);
    u32 r = (x + 0x7FFFu + ((x >> 16) & 1u)) >> 16;
    return (u16)r;
}
static __device__ __forceinline__ float bf2f(u16 u) {
    return __uint_as_float(((u32)u) << 16);
}
static __device__ __forceinline__ u32 pk2(float lo, float hi) {
    __hip_bfloat162 t = __float22bfloat162_rn(float2{lo, hi});
    union { __hip_bfloat162 b; u32 u; } cv;
    cv.b = t;
    return cv.u;
}

static __device__ __forceinline__ void g2l16(const void* g, void* l) {
    __builtin_amdgcn_global_load_lds((const __attribute__((address_space(1))) void*)g,
                                     (__attribute__((address_space(3))) void*)l, 16, 0, 0);
}

// ---------------------------------------------------------------- convert (2 tensors)
__global__ __launch_bounds__(256) void k_cvt2(const float* __restrict__ a0,
                                              const float* __restrict__ a1,
                                              u16* __restrict__ o0,
                                              u16* __restrict__ o1, int n8) {
    const float* in = blockIdx.y ? a1 : a0;
    u16* out = blockIdx.y ? o1 : o0;
    int i = blockIdx.x * 256 + threadIdx.x;
    if (i >= n8) return;
    const float4* p = (const float4*)in + (size_t)i * 2;
    float4 a = p[0], b = p[1];
    short8 o;
    o[0] = f2bf(a.x); o[1] = f2bf(a.y); o[2] = f2bf(a.z); o[3] = f2bf(a.w);
    o[4] = f2bf(b.x); o[5] = f2bf(b.y); o[6] = f2bf(b.z); o[7] = f2bf(b.w);
    *((short8*)out + i) = o;
}

// ---------------------------------------------------------------- convert (4 weights)
__global__ __launch_bounds__(256) void k_cvt4(
    const float* __restrict__ a0, const float* __restrict__ a1,
    const float* __restrict__ a2, const float* __restrict__ a3,
    u16* __restrict__ o0, u16* __restrict__ o1, u16* __restrict__ o2,
    u16* __restrict__ o3, int n8) {
    const float* in = (blockIdx.y == 0) ? a0 : (blockIdx.y == 1) ? a1
                      : (blockIdx.y == 2) ? a2 : a3;
    u16* out = (blockIdx.y == 0) ? o0 : (blockIdx.y == 1) ? o1
               : (blockIdx.y == 2) ? o2 : o3;
    int i = blockIdx.x * 256 + threadIdx.x;
    if (i >= n8) return;
    const float4* p = (const float4*)in + (size_t)i * 2;
    float4 a = p[0], b = p[1];
    short8 o;
    o[0] = f2bf(a.x); o[1] = f2bf(a.y); o[2] = f2bf(a.z); o[3] = f2bf(a.w);
    o[4] = f2bf(b.x); o[5] = f2bf(b.y); o[6] = f2bf(b.z); o[7] = f2bf(b.w);
    *((short8*)out + i) = o;
}

// ---------------------------------------------------------------- gates
__global__ __launch_bounds__(256) void k_gates(
    const float* __restrict__ qin, const float* __restrict__ Wdy2,
    const float* __restrict__ bdy2, const float* __restrict__ Wdy,
    const float* __restrict__ bdy, const float* __restrict__ star_s,
    const float* __restrict__ star_b, float* __restrict__ glf,
    float* __restrict__ ghf) {
    __shared__ __align__(16) u16 wl[2][12 * 768];
    for (int idx = threadIdx.x; idx < 9216; idx += 256) {
        wl[0][idx] = f2bf(Wdy2[idx]);
        wl[1][idx] = f2bf(Wdy[idx]);
    }
    __syncthreads();
    int w = threadIdx.x >> 6, lane = threadIdx.x & 63;
    float ss = star_s[0], sb = star_b[0];
    int t0 = blockIdx.x * 32 + w * 8;
    for (int tt = 0; tt < 8; ++tt) {
        int t = t0 + tt;
        float sr[12];
#pragma unroll
        for (int i = 0; i < 12; ++i) {
            float x = qin[(size_t)t * 768 + lane + 64 * i];
            x = fmaxf(x, 0.f);
            sr[i] = ss * x * x + sb;
        }
        float acc[24];
#pragma unroll
        for (int h = 0; h < 24; ++h) acc[h] = 0.f;
#pragma unroll
        for (int i = 0; i < 12; ++i) {
#pragma unroll
            for (int h = 0; h < 12; ++h) {
                acc[h]      += sr[i] * bf2f(wl[0][h * 768 + lane + 64 * i]);
                acc[12 + h] += sr[i] * bf2f(wl[1][h * 768 + lane + 64 * i]);
            }
        }
        float keep = 0.f;
#pragma unroll
        for (int h = 0; h < 24; ++h) {
            float v = acc[h];
#pragma unroll
            for (int msk = 1; msk < 64; msk <<= 1) v += __shfl_xor(v, msk);
            if (lane == h) keep = v;
        }
        if (lane < 12) {
            glf[(size_t)t * 12 + lane] = tanhf(keep + bdy2[lane]);
        } else if (lane < 24) {
            float x = keep + bdy[lane - 12];
            float sp = (x > 15.f) ? x : log1pf(expf(x));
            float d2 = sp * sp;
            ghf[(size_t)t * 12 + (lane - 12)] = 2.f * d2 / (d2 + 0.3678f);
        }
    }
}

// ---------------------------------------------------------------- GEMM core
__device__ __forceinline__ void gemm_core(const u16* __restrict__ A,
                                          const u16* __restrict__ W, u16* As,
                                          u16* Bs, int rowA0, int rowB0,
                                          int lane, int w, int wm, int wn,
                                          f32x4 acc[4][4]) {
#pragma unroll
    for (int m = 0; m < 4; ++m)
#pragma unroll
        for (int n = 0; n < 4; ++n) acc[m][n] = (f32x4){0.f, 0.f, 0.f, 0.f};

    auto stage = [&](int buf, int k0) {
#pragma unroll
        for (int j = 0; j < 2; ++j) {
            int idx = w * 128 + j * 64 + lane;
            g2l16(A + (size_t)(rowA0 + (idx >> 2)) * 768 + k0 + (idx & 3) * 8,
                  As + buf * 4096 + (w * 128 + j * 64) * 8);
            g2l16(W + (size_t)(rowB0 + (idx >> 2)) * 768 + k0 + (idx & 3) * 8,
                  Bs + buf * 4096 + (w * 128 + j * 64) * 8);
        }
    };

    stage(0, 0);
    __syncthreads();
    int buf = 0;
    for (int t = 0; t < 24; ++t) {
        if (t < 23) stage(buf ^ 1, (t + 1) * 32);
        short8 a[4], b[4];
#pragma unroll
        for (int m = 0; m < 4; ++m)
            a[m] = *(const short8*)(As + buf * 4096 +
                                    (wm * 64 + m * 16 + (lane & 15)) * 32 +
                                    (lane >> 4) * 8);
#pragma unroll
        for (int n = 0; n < 4; ++n)
            b[n] = *(const short8*)(Bs + buf * 4096 +
                                    (wn * 64 + n * 16 + (lane & 15)) * 32 +
                                    (lane >> 4) * 8);
#pragma unroll
        for (int m = 0; m < 4; ++m)
#pragma unroll
            for (int n = 0; n < 4; ++n)
                acc[m][n] = __builtin_amdgcn_mfma_f32_16x16x32_bf16(
                    a[m], b[n], acc[m][n], 0, 0, 0);
        __syncthreads();
        buf ^= 1;
    }
}

// ---------------------------------------------------------------- QKV GEMM
__global__ __launch_bounds__(256, 2) void k_gemm_qkv(
    const u16* __restrict__ qbf, const u16* __restrict__ kvbf,
    const u16* __restrict__ Wqb, const u16* __restrict__ Wkb,
    const u16* __restrict__ Wvb, u16* __restrict__ Qb, u16* __restrict__ Kb,
    u16* __restrict__ VTg, u16* __restrict__ vlin) {
    __shared__ __align__(16) u16 smem[16384];
    u16* As = smem;
    u16* Bs = smem + 8192;
    int mode = blockIdx.z;
    const u16* A = (mode == 0) ? qbf : kvbf;
    const u16* W = (mode == 0) ? Wqb : (mode == 1 ? Wkb : Wvb);
    int bid = blockIdx.x;
    int tm = bid / 6, tn = bid % 6;
    int tid = threadIdx.x, lane = tid & 63, w = tid >> 6;
    int wm = w >> 1, wn = w & 1;
    int rowA0 = tm * 128, rowB0 = tn * 128;

    f32x4 acc[4][4];
    gemm_core(A, W, As, Bs, rowA0, rowB0, lane, w, wm, wn, acc);

    if (mode < 2) {
        u16* dst = (mode == 0) ? Qb : Kb;
        const float scl = (mode == 0) ? (0.125f * LOG2E) : 1.0f;
#pragma unroll
        for (int m = 0; m < 4; ++m)
#pragma unroll
            for (int n = 0; n < 4; ++n)
#pragma unroll
                for (int r = 0; r < 4; ++r) {
                    int row = rowA0 + wm * 64 + m * 16 + (lane >> 4) * 4 + r;
                    int col = rowB0 + wn * 64 + n * 16 + (lane & 15);
                    int bb = row >> 10, nn = row & 1023, hh = col >> 6,
                        dd = col & 63;
                    dst[((size_t)(bb * 12 + hh) << 16) + (nn << 6) + dd] =
                        f2bf(acc[m][n][r] * scl);
                }
    } else {
#pragma unroll
        for (int m = 0; m < 4; ++m)
#pragma unroll
            for (int n = 0; n < 4; ++n)
#pragma unroll
                for (int r = 0; r < 4; ++r) {
                    int row = rowA0 + wm * 64 + m * 16 + (lane >> 4) * 4 + r;
                    int col = rowB0 + wn * 64 + n * 16 + (lane & 15);
                    vlin[(size_t)row * 768 + col] = f2bf(acc[m][n][r]);
                }
        __syncthreads();
        // transpose C tile (128 tokens x 128 douts) through LDS
#pragma unroll
        for (int m = 0; m < 4; ++m)
#pragma unroll
            for (int n = 0; n < 4; ++n)
#pragma unroll
                for (int r = 0; r < 4; ++r) {
                    int rl = wm * 64 + m * 16 + (lane >> 4) * 4 + r;
                    int cl = wn * 64 + n * 16 + (lane & 15);
                    smem[cl * 128 + rl] = f2bf(acc[m][n][r]);
                }
        __syncthreads();
        int bb = rowA0 >> 10, nn0 = rowA0 & 1023;
        // write V^T with per-64-token k-permutation rho (PV fragment-ready)
#pragma unroll
        for (int j = 0; j < 8; ++j) {
            int idx = j * 256 + tid;
            int rT = idx >> 4, cc = idx & 15;
            int dout = rowB0 + rT, hh = dout >> 6, dd = dout & 63;
            const u16* srow = smem + rT * 128 + cc * 8;
            size_t robase = ((size_t)(bb * 12 + hh) * 64 + dd) * 1024;
#pragma unroll
            for (int e2 = 0; e2 < 4; ++e2) {
                int n0 = nn0 + cc * 8 + 2 * e2;
                int t6 = n0 & 63;
                int pos = (((t6 >> 1) & 1) << 5) | (((t6 >> 2) & 3) << 3) |
                          (((t6 >> 4) & 3) << 1) | (t6 & 1);
                u32 val = (u32)srow[2 * e2] | ((u32)srow[2 * e2 + 1] << 16);
                *(u32*)(VTg + robase + (n0 & ~63) + pos) = val;
            }
        }
    }
}

// ---------------------------------------------------------------- out GEMM
__global__ __launch_bounds__(256, 2) void k_gemm_out(
    const u16* __restrict__ xf, const u16* __restrict__ Wpb,
    const float* __restrict__ bp, float* __restrict__ out) {
    __shared__ __align__(16) u16 smem[16384];
    u16* As = smem;
    u16* Bs = smem + 8192;
    int bid = blockIdx.x;
    int tm = bid / 6, tn = bid % 6;
    int tid = threadIdx.x, lane = tid & 63, w = tid >> 6;
    int wm = w >> 1, wn = w & 1;
    int rowA0 = tm * 128, rowB0 = tn * 128;

    f32x4 acc[4][4];
    gemm_core(xf, Wpb, As, Bs, rowA0, rowB0, lane, w, wm, wn, acc);

#pragma unroll
    for (int m = 0; m < 4; ++m)
#pragma unroll
        for (int n = 0; n < 4; ++n)
#pragma unroll
            for (int r = 0; r < 4; ++r) {
                int row = rowA0 + wm * 64 + m * 16 + (lane >> 4) * 4 + r;
                int col = rowB0 + wn * 64 + n * 16 + (lane & 15);
                out[(size_t)row * 768 + col] = acc[m][n][r] + bp[col];
            }
}

// ---------------------------------------------------------------- attention
// swapped QK^T (mfma(K,Q)), no max subtraction (scores bounded ~2),
// P->A-fragment via register identity (V^T pre-permuted), swizzled LDS.
__global__ __launch_bounds__(256, 2) void k_attn(const u16* __restrict__ Qb,
                                                 const u16* __restrict__ Kb,
                                                 const u16* __restrict__ VTg,
                                                 u16* __restrict__ xattn) {
    __shared__ __align__(16) u16 Ks[2][4096];
    __shared__ __align__(16) u16 Vs[2][4096];
    int b8 = blockIdx.x;
    int sw = (b8 & 7) * 96 + (b8 >> 3);  // XCD clustering: 12 heads per XCD
    int bh = sw >> 3, qblk = sw & 7;
    int bb = bh / 12, hh = bh % 12;
    int tid = threadIdx.x, lane = tid & 63, w = tid >> 6;
    int g = lane >> 4, c = lane & 15;
    const char* Kp = (const char*)(Kb + ((size_t)bh << 16));
    const char* Vp = (const char*)(VTg + ((size_t)bh << 16));
    const u16* Qp = Qb + ((size_t)bh << 16);
    int q0 = qblk * 128 + w * 32;

    // Q B-fragments (already scaled by 0.125*log2e at projection)
    short8 qf[2][2];
#pragma unroll
    for (int qb = 0; qb < 2; ++qb)
#pragma unroll
        for (int ks = 0; ks < 2; ++ks)
            qf[qb][ks] = *(const short8*)(Qp + (size_t)(q0 + qb * 16 + c) * 64 +
                                          ks * 32 + g * 8);

    f32x4 o[2][4];
#pragma unroll
    for (int qb = 0; qb < 2; ++qb)
#pragma unroll
        for (int n = 0; n < 4; ++n) o[qb][n] = (f32x4){0.f, 0.f, 0.f, 0.f};
    float lsum[2] = {0.f, 0.f};

    // staging addresses (source pre-swizzled, LDS dest linear)
    int kgo[2], vgo[2], ldo[2];
#pragma unroll
    for (int h = 0; h < 2; ++h) {
        int idx = w * 64 + lane + h * 256;
        int row = idx >> 3;
        int colb = ((idx & 7) * 16) ^ ((row & 7) << 4);
        kgo[h] = row * 128 + colb;
        vgo[h] = row * 2048 + colb;
        ldo[h] = (w * 64 + h * 256) * 16;
    }

    auto stage = [&](int bi, int t) {
#pragma unroll
        for (int h = 0; h < 2; ++h) {
            g2l16(Kp + (size_t)t * 8192 + kgo[h], (char*)&Ks[bi][0] + ldo[h]);
            g2l16(Vp + (size_t)t * 128 + vgo[h], (char*)&Vs[bi][0] + ldo[h]);
        }
    };

    stage(0, 0);
    __syncthreads();
    int buf = 0;
    int cs = (c & 7) << 4;
    for (int t = 0; t < 16; ++t) {
        if (t < 15) stage(buf ^ 1, t + 1);
        const char* Kbase = (const char*)&Ks[buf][0];
        const char* Vbase = (const char*)&Vs[buf][0];
        short8 kf[4][2], vf[4][2];
#pragma unroll
        for (int m = 0; m < 4; ++m) {
            int rowb = (m * 16 + c) * 128;
#pragma unroll
            for (int ks = 0; ks < 2; ++ks)
                kf[m][ks] = *(const short8*)(Kbase + rowb +
                                             ((g * 16 + ks * 64) ^ cs));
        }
#pragma unroll
        for (int n = 0; n < 4; ++n) {
            int rowb = (n * 16 + c) * 128;
#pragma unroll
            for (int a = 0; a < 2; ++a)
                vf[n][a] = *(const short8*)(Vbase + rowb +
                                            ((a * 64 + g * 16) ^ cs));
        }
#pragma unroll
        for (int qb = 0; qb < 2; ++qb) {
            f32x4 s[4];
            __builtin_amdgcn_s_setprio(1);
#pragma unroll
            for (int m = 0; m < 4; ++m) {
                s[m] = __builtin_amdgcn_mfma_f32_16x16x32_bf16(
                    kf[m][0], qf[qb][0], (f32x4){0.f, 0.f, 0.f, 0.f}, 0, 0, 0);
                s[m] = __builtin_amdgcn_mfma_f32_16x16x32_bf16(
                    kf[m][1], qf[qb][1], s[m], 0, 0, 0);
            }
            __builtin_amdgcn_s_setprio(0);
            u32 P2[4][2];
            float ls = 0.f;
#pragma unroll
            for (int m = 0; m < 4; ++m) {
#pragma unroll
                for (int r = 0; r < 4; ++r) {
                    s[m][r] = exp2f(s[m][r]);
                    ls += s[m][r];
                }
                P2[m][0] = pk2(s[m][0], s[m][1]);
                P2[m][1] = pk2(s[m][2], s[m][3]);
            }
            lsum[qb] += ls;
#pragma unroll
            for (int a = 0; a < 2; ++a) {
                union { u32 u[4]; short8 s8; } pu;
                pu.u[0] = P2[0][a]; pu.u[1] = P2[1][a];
                pu.u[2] = P2[2][a]; pu.u[3] = P2[3][a];
                __builtin_amdgcn_s_setprio(1);
#pragma unroll
                for (int n = 0; n < 4; ++n)
                    o[qb][n] = __builtin_amdgcn_mfma_f32_16x16x32_bf16(
                        pu.s8, vf[n][a], o[qb][n], 0, 0, 0);
                __builtin_amdgcn_s_setprio(0);
            }
        }
        __syncthreads();
        buf ^= 1;
    }

#pragma unroll
    for (int qb = 0; qb < 2; ++qb) {
        float L = lsum[qb];
        L += __shfl_xor(L, 16);
        L += __shfl_xor(L, 32);
        float rl[4];
#pragma unroll
        for (int r = 0; r < 4; ++r) rl[r] = 1.0f / __shfl(L, g * 4 + r);
#pragma unroll
        for (int n = 0; n < 4; ++n)
#pragma unroll
            for (int r = 0; r < 4; ++r) {
                int q = q0 + qb * 16 + 4 * g + r;
                int d = n * 16 + c;
                xattn[(size_t)(bb * 1024 + q) * 768 + hh * 64 + d] =
                    f2bf(o[qb][n][r] * rl[r]);
            }
    }
}

// ---------------------------------------------------------------- combine
__global__ __launch_bounds__(256) void k_combine(
    const u16* __restrict__ xattn, const u16* __restrict__ vlin,
    const float* __restrict__ glf, const float* __restrict__ ghf,
    const float* __restrict__ lfg, const float* __restrict__ hfg,
    u16* __restrict__ xfinal) {
    int i = blockIdx.x * 256 + threadIdx.x;
    size_t base = (size_t)i * 8;
    int c = (int)(base % 768);
    int t = (int)(base / 768);
    int h = c >> 6;
    float a_lf = glf[(size_t)t * 12 + h];
    float a_hf = ghf[(size_t)t * 12 + h];
    short8 xa8 = *((const short8*)xattn + i);
    short8 vl8 = *((const short8*)vlin + i);
    float4 lg0 = *(const float4*)(lfg + c);
    float4 lg1 = *(const float4*)(lfg + c + 4);
    float4 hg0 = *(const float4*)(hfg + c);
    float4 hg1 = *(const float4*)(hfg + c + 4);
    float lg[8] = {lg0.x, lg0.y, lg0.z, lg0.w, lg1.x, lg1.y, lg1.z, lg1.w};
    float hg[8] = {hg0.x, hg0.y, hg0.z, hg0.w, hg1.x, hg1.y, hg1.z, hg1.w};
    short8 o;
#pragma unroll
    for (int j = 0; j < 8; ++j) {
        float xa = bf2f((u16)xa8[j]);
        float v = bf2f((u16)vl8[j]);
        float val = xa + xa * a_lf * lg[j] + a_hf * (v - xa) * hg[j];
        o[j] = f2bf(val);
    }
    *((short8*)xfinal + i) = o;
}

// ---------------------------------------------------------------- launch
extern "C" void kernel_launch(void* const* d_in, const int* in_sizes, int n_in,
                              void* d_out, int out_size, void* d_ws,
                              size_t ws_size, hipStream_t stream) {
    const float* q_in = (const float*)d_in[0];
    const float* kv_in = (const float*)d_in[1];
    const float* Wq = (const float*)d_in[2];
    const float* Wk = (const float*)d_in[3];
    const float* Wv = (const float*)d_in[4];
    const float* Wp = (const float*)d_in[5];
    const float* bp = (const float*)d_in[6];
    const float* Wdy2 = (const float*)d_in[7];
    const float* bdy2 = (const float*)d_in[8];
    const float* Wdy = (const float*)d_in[9];
    const float* bdy = (const float*)d_in[10];
    const float* lfg = (const float*)d_in[11];
    const float* hfg = (const float*)d_in[12];
    const float* st_s = (const float*)d_in[13];
    const float* st_b = (const float*)d_in[14];
    float* out = (float*)d_out;

    char* ws = (char*)d_ws;
    const size_t MC2 = (size_t)8192 * 768 * 2;
    const size_t WB = (size_t)768 * 768 * 2;
    u16* qbf = (u16*)(ws);
    u16* kvbf = (u16*)(ws + MC2);
    u16* Wqb = (u16*)(ws + 2 * MC2);
    u16* Wkb = (u16*)(ws + 2 * MC2 + WB);
    u16* Wvb = (u16*)(ws + 2 * MC2 + 2 * WB);
    u16* Wpb = (u16*)(ws + 2 * MC2 + 3 * WB);
    u16* Qb = (u16*)(ws + 2 * MC2 + 4 * WB);
    u16* Kb = (u16*)(ws + 3 * MC2 + 4 * WB);
    u16* VTg = (u16*)(ws + 4 * MC2 + 4 * WB);
    u16* vlin = (u16*)(ws + 5 * MC2 + 4 * WB);
    float* glf = (float*)(ws + 6 * MC2 + 4 * WB);
    float* ghf = (float*)(ws + 6 * MC2 + 4 * WB + (size_t)8192 * 12 * 4);
    u16* xattn = kvbf;
    u16* xfinal = qbf;

    k_cvt2<<<dim3(3072, 2), 256, 0, stream>>>(q_in, kv_in, qbf, kvbf, 786432);
    k_cvt4<<<dim3(288, 4), 256, 0, stream>>>(Wq, Wk, Wv, Wp, Wqb, Wkb, Wvb,
                                             Wpb, 73728);
    k_gates<<<256, 256, 0, stream>>>(q_in, Wdy2, bdy2, Wdy, bdy, st_s, st_b,
                                     glf, ghf);
    k_gemm_qkv<<<dim3(384, 1, 3), 256, 0, stream>>>(qbf, kvbf, Wqb, Wkb, Wvb,
                                                    Qb, Kb, VTg, vlin);
    k_attn<<<768, 256, 0, stream>>>(Qb, Kb, VTg, xattn);
    k_combine<<<3072, 256, 0, stream>>>(xattn, vlin, glf, ghf, lfg, hfg,
                                        xfinal);
    k_gemm_out<<<384, 256, 0, stream>>>(xfinal, Wpb, bp, out);
}

// Round 3
// 195.008 us; speedup vs baseline: 1.5367x; 1.1030x over previous
//
#include <hip/hip_runtime.h>
#include <hip/hip_bf16.h>
#include <stdint.h>

typedef unsigned short u16;
typedef unsigned int u32;
typedef unsigned long long u64;
typedef __attribute__((ext_vector_type(8))) short short8;
typedef __attribute__((ext_vector_type(4))) float f32x4;

#define LOG2E 1.44269504f

static __device__ __forceinline__ u16 f2bf(float f) {
    u32 x = __float_as_uint(f);
    u32 r = (x + 0x7FFFu + ((x >> 16) & 1u)) >> 16;
    return (u16)r;
}
static __device__ __forceinline__ float bf2f(u16 u) {
    return __uint_as_float(((u32)u) << 16);
}
static __device__ __forceinline__ u32 pk2(float lo, float hi) {
    __hip_bfloat162 t = __float22bfloat162_rn(float2{lo, hi});
    union { __hip_bfloat162 b; u32 u; } cv;
    cv.b = t;
    return cv.u;
}

static __device__ __forceinline__ void g2l16(const void* g, void* l) {
    __builtin_amdgcn_global_load_lds((const __attribute__((address_space(1))) void*)g,
                                     (__attribute__((address_space(3))) void*)l, 16, 0, 0);
}

// ---------------------------------------------------------------- convert (2 tensors)
__global__ __launch_bounds__(256) void k_cvt2(const float* __restrict__ a0,
                                              const float* __restrict__ a1,
                                              u16* __restrict__ o0,
                                              u16* __restrict__ o1, int n8) {
    const float* in = blockIdx.y ? a1 : a0;
    u16* out = blockIdx.y ? o1 : o0;
    int i = blockIdx.x * 256 + threadIdx.x;
    if (i >= n8) return;
    const float4* p = (const float4*)in + (size_t)i * 2;
    float4 a = p[0], b = p[1];
    short8 o;
    o[0] = f2bf(a.x); o[1] = f2bf(a.y); o[2] = f2bf(a.z); o[3] = f2bf(a.w);
    o[4] = f2bf(b.x); o[5] = f2bf(b.y); o[6] = f2bf(b.z); o[7] = f2bf(b.w);
    *((short8*)out + i) = o;
}

// ---------------------------------------------------------------- convert (4 weights)
__global__ __launch_bounds__(256) void k_cvt4(
    const float* __restrict__ a0, const float* __restrict__ a1,
    const float* __restrict__ a2, const float* __restrict__ a3,
    u16* __restrict__ o0, u16* __restrict__ o1, u16* __restrict__ o2,
    u16* __restrict__ o3, int n8) {
    const float* in = (blockIdx.y == 0) ? a0 : (blockIdx.y == 1) ? a1
                      : (blockIdx.y == 2) ? a2 : a3;
    u16* out = (blockIdx.y == 0) ? o0 : (blockIdx.y == 1) ? o1
               : (blockIdx.y == 2) ? o2 : o3;
    int i = blockIdx.x * 256 + threadIdx.x;
    if (i >= n8) return;
    const float4* p = (const float4*)in + (size_t)i * 2;
    float4 a = p[0], b = p[1];
    short8 o;
    o[0] = f2bf(a.x); o[1] = f2bf(a.y); o[2] = f2bf(a.z); o[3] = f2bf(a.w);
    o[4] = f2bf(b.x); o[5] = f2bf(b.y); o[6] = f2bf(b.z); o[7] = f2bf(b.w);
    *((short8*)out + i) = o;
}

// ---------------------------------------------------------------- gates (MFMA mini-GEMM)
// (8192 x 768) feat @ (768 x 32) Wg^T, feat computed in-kernel from q_in.
__global__ __launch_bounds__(256) void k_gates_mm(
    const float* __restrict__ qin, const float* __restrict__ Wdy2,
    const float* __restrict__ bdy2, const float* __restrict__ Wdy,
    const float* __restrict__ bdy, const float* __restrict__ star_s,
    const float* __restrict__ star_b, float* __restrict__ glf,
    float* __restrict__ ghf) {
    __shared__ __align__(16) u16 Bs[32 * 776];  // padded rows: 776 u16
    __shared__ __align__(16) u16 Asm[64 * 40];  // padded rows: 40 u16
    int tid = threadIdx.x, lane = tid & 63, w = tid >> 6;
    int g = lane >> 4, c = lane & 15;
    // stage gate weights once: rows 0-11 = Wdy2, 12-23 = Wdy, 24-31 = 0
    for (int idx = tid; idx < 32 * 768; idx += 256) {
        int row = idx / 768, col = idx % 768;
        float v = 0.f;
        if (row < 12) v = Wdy2[row * 768 + col];
        else if (row < 24) v = Wdy[(row - 12) * 768 + col];
        Bs[row * 776 + col] = f2bf(v);
    }
    float ss = star_s[0], sb = star_b[0];
    int row0 = blockIdx.x * 64;
    f32x4 acc[2];
    acc[0] = (f32x4){0.f, 0.f, 0.f, 0.f};
    acc[1] = (f32x4){0.f, 0.f, 0.f, 0.f};
    __syncthreads();
    for (int t = 0; t < 24; ++t) {
        int k0 = t * 32;
#pragma unroll
        for (int e = 0; e < 2; ++e) {
            int lin = e * 1024 + tid * 4;
            int rr = lin >> 5, cc = lin & 31;
            float4 x4 = *(const float4*)(qin + (size_t)(row0 + rr) * 768 + k0 + cc);
            float xs[4] = {x4.x, x4.y, x4.z, x4.w};
            u64 pk = 0;
#pragma unroll
            for (int j = 0; j < 4; ++j) {
                float x = fmaxf(xs[j], 0.f);
                pk |= ((u64)f2bf(ss * x * x + sb)) << (16 * j);
            }
            *(u64*)(Asm + rr * 40 + cc) = pk;
        }
        __syncthreads();
        short8 a = *(const short8*)(Asm + (w * 16 + c) * 40 + g * 8);
#pragma unroll
        for (int n = 0; n < 2; ++n) {
            short8 b = *(const short8*)(Bs + (n * 16 + c) * 776 + k0 + g * 8);
            acc[n] = __builtin_amdgcn_mfma_f32_16x16x32_bf16(a, b, acc[n], 0, 0, 0);
        }
        __syncthreads();
    }
#pragma unroll
    for (int n = 0; n < 2; ++n)
#pragma unroll
        for (int r = 0; r < 4; ++r) {
            int row = row0 + w * 16 + g * 4 + r;
            int col = n * 16 + c;
            float v = acc[n][r];
            if (col < 12) {
                glf[(size_t)row * 12 + col] = tanhf(v + bdy2[col]);
            } else if (col < 24) {
                float x = v + bdy[col - 12];
                float sp = (x > 15.f) ? x : log1pf(expf(x));
                float d2 = sp * sp;
                ghf[(size_t)row * 12 + (col - 12)] = 2.f * d2 / (d2 + 0.3678f);
            }
        }
}

// ---------------------------------------------------------------- QKV GEMM (Q blocks + KV-fused blocks)
__global__ __launch_bounds__(256, 2) void k_gemm_qkv(
    const u16* __restrict__ qbf, const u16* __restrict__ kvbf,
    const u16* __restrict__ Wqb, const u16* __restrict__ Wkb,
    const u16* __restrict__ Wvb, u16* __restrict__ Qb, u16* __restrict__ Kb,
    u16* __restrict__ VTg, u16* __restrict__ vlin) {
    __shared__ __align__(16) u16 smem[24576];  // 48 KB
    u16* As = smem;          // [2][4096]
    u16* B0 = smem + 8192;   // [2][4096]
    u16* B1 = smem + 16384;  // [2][4096]
    int bid = blockIdx.x;
    // XCD-chunked: chunk = bid&7 gets 96 consecutive logical blocks
    // (8 row panels x (6 Q-tiles + 6 KV-tiles)) -> A panels stay in XCD L2.
    int logical = (bid & 7) * 96 + (bid >> 3);
    int c96 = logical % 96;
    int tmL = c96 / 12, r12 = c96 % 12;
    bool kv = (r12 >= 6);
    int tn = r12 % 6;
    int tm = (logical / 96) * 8 + tmL;
    int tid = threadIdx.x, lane = tid & 63, w = tid >> 6;
    int g = lane >> 4, c = lane & 15;
    int wm = w >> 1, wn = w & 1;
    int rowA0 = tm * 128, rowB0 = tn * 128;
    const u16* A = kv ? kvbf : qbf;
    const u16* W0 = kv ? Wkb : Wqb;

    f32x4 acc0[4][4], acc1[4][4];
#pragma unroll
    for (int m = 0; m < 4; ++m)
#pragma unroll
        for (int n = 0; n < 4; ++n) {
            acc0[m][n] = (f32x4){0.f, 0.f, 0.f, 0.f};
            acc1[m][n] = (f32x4){0.f, 0.f, 0.f, 0.f};
        }

    auto stage = [&](int buf, int k0) {
#pragma unroll
        for (int j = 0; j < 2; ++j) {
            int idx = w * 128 + j * 64 + lane;
            size_t go = (size_t)(idx >> 2) * 768 + k0 + (idx & 3) * 8;
            int lo = (w * 128 + j * 64) * 8;
            g2l16(A + (size_t)rowA0 * 768 + go, As + buf * 4096 + lo);
            g2l16(W0 + (size_t)rowB0 * 768 + go, B0 + buf * 4096 + lo);
            if (kv) g2l16(Wvb + (size_t)rowB0 * 768 + go, B1 + buf * 4096 + lo);
        }
    };

    stage(0, 0);
    __syncthreads();
    int buf = 0;
    for (int t = 0; t < 24; ++t) {
        if (t < 23) stage(buf ^ 1, (t + 1) * 32);
        short8 a[4], b0[4], b1[4];
#pragma unroll
        for (int m = 0; m < 4; ++m)
            a[m] = *(const short8*)(As + buf * 4096 +
                                    (wm * 64 + m * 16 + c) * 32 + g * 8);
#pragma unroll
        for (int n = 0; n < 4; ++n)
            b0[n] = *(const short8*)(B0 + buf * 4096 +
                                     (wn * 64 + n * 16 + c) * 32 + g * 8);
        if (kv) {
#pragma unroll
            for (int n = 0; n < 4; ++n)
                b1[n] = *(const short8*)(B1 + buf * 4096 +
                                         (wn * 64 + n * 16 + c) * 32 + g * 8);
        }
#pragma unroll
        for (int m = 0; m < 4; ++m)
#pragma unroll
            for (int n = 0; n < 4; ++n)
                acc0[m][n] = __builtin_amdgcn_mfma_f32_16x16x32_bf16(
                    a[m], b0[n], acc0[m][n], 0, 0, 0);
        if (kv) {
#pragma unroll
            for (int m = 0; m < 4; ++m)
#pragma unroll
                for (int n = 0; n < 4; ++n)
                    acc1[m][n] = __builtin_amdgcn_mfma_f32_16x16x32_bf16(
                        a[m], b1[n], acc1[m][n], 0, 0, 0);
        }
        __syncthreads();
        buf ^= 1;
    }

    if (!kv) {
        const float scl = 0.125f * LOG2E;
#pragma unroll
        for (int m = 0; m < 4; ++m)
#pragma unroll
            for (int n = 0; n < 4; ++n)
#pragma unroll
                for (int r = 0; r < 4; ++r) {
                    int row = rowA0 + wm * 64 + m * 16 + g * 4 + r;
                    int col = rowB0 + wn * 64 + n * 16 + c;
                    int bb = row >> 10, nn = row & 1023, hh = col >> 6,
                        dd = col & 63;
                    Qb[((size_t)(bb * 12 + hh) << 16) + (nn << 6) + dd] =
                        f2bf(acc0[m][n][r] * scl);
                }
    } else {
#pragma unroll
        for (int m = 0; m < 4; ++m)
#pragma unroll
            for (int n = 0; n < 4; ++n)
#pragma unroll
                for (int r = 0; r < 4; ++r) {
                    int row = rowA0 + wm * 64 + m * 16 + g * 4 + r;
                    int col = rowB0 + wn * 64 + n * 16 + c;
                    int bb = row >> 10, nn = row & 1023, hh = col >> 6,
                        dd = col & 63;
                    Kb[((size_t)(bb * 12 + hh) << 16) + (nn << 6) + dd] =
                        f2bf(acc0[m][n][r]);
                    vlin[(size_t)row * 768 + col] = f2bf(acc1[m][n][r]);
                }
        __syncthreads();
        // transpose V tile (128 tokens x 128 douts) through LDS
#pragma unroll
        for (int m = 0; m < 4; ++m)
#pragma unroll
            for (int n = 0; n < 4; ++n)
#pragma unroll
                for (int r = 0; r < 4; ++r) {
                    int rl = wm * 64 + m * 16 + g * 4 + r;
                    int cl = wn * 64 + n * 16 + c;
                    smem[cl * 128 + rl] = f2bf(acc1[m][n][r]);
                }
        __syncthreads();
        int bb = rowA0 >> 10, nn0 = rowA0 & 1023;
        // write V^T with per-64-token k-permutation rho (PV fragment-ready)
#pragma unroll
        for (int j = 0; j < 8; ++j) {
            int idx = j * 256 + tid;
            int rT = idx >> 4, cc = idx & 15;
            int dout = rowB0 + rT, hh = dout >> 6, dd = dout & 63;
            const u16* srow = smem + rT * 128 + cc * 8;
            size_t robase = ((size_t)(bb * 12 + hh) * 64 + dd) * 1024;
#pragma unroll
            for (int e2 = 0; e2 < 4; ++e2) {
                int n0 = nn0 + cc * 8 + 2 * e2;
                int t6 = n0 & 63;
                int pos = (((t6 >> 1) & 1) << 5) | (((t6 >> 2) & 3) << 3) |
                          (((t6 >> 4) & 3) << 1) | (t6 & 1);
                u32 val = (u32)srow[2 * e2] | ((u32)srow[2 * e2 + 1] << 16);
                *(u32*)(VTg + robase + (n0 & ~63) + pos) = val;
            }
        }
    }
}

// ---------------------------------------------------------------- out GEMM
__global__ __launch_bounds__(256, 2) void k_gemm_out(
    const u16* __restrict__ xf, const u16* __restrict__ Wpb,
    const float* __restrict__ bp, float* __restrict__ out) {
    __shared__ __align__(16) u16 smem[16384];
    u16* As = smem;
    u16* Bs = smem + 8192;
    int bid = blockIdx.x;
    int logical = (bid & 7) * 48 + (bid >> 3);
    int c48 = logical % 48;
    int tm = (logical / 48) * 8 + c48 / 6, tn = c48 % 6;
    int tid = threadIdx.x, lane = tid & 63, w = tid >> 6;
    int wm = w >> 1, wn = w & 1;
    int rowA0 = tm * 128, rowB0 = tn * 128;

    f32x4 acc[4][4];
#pragma unroll
    for (int m = 0; m < 4; ++m)
#pragma unroll
        for (int n = 0; n < 4; ++n) acc[m][n] = (f32x4){0.f, 0.f, 0.f, 0.f};

    auto stage = [&](int buf, int k0) {
#pragma unroll
        for (int j = 0; j < 2; ++j) {
            int idx = w * 128 + j * 64 + lane;
            size_t go = (size_t)(idx >> 2) * 768 + k0 + (idx & 3) * 8;
            int lo = (w * 128 + j * 64) * 8;
            g2l16(xf + (size_t)rowA0 * 768 + go, As + buf * 4096 + lo);
            g2l16(Wpb + (size_t)rowB0 * 768 + go, Bs + buf * 4096 + lo);
        }
    };

    stage(0, 0);
    __syncthreads();
    int buf = 0;
    for (int t = 0; t < 24; ++t) {
        if (t < 23) stage(buf ^ 1, (t + 1) * 32);
        short8 a[4], b[4];
#pragma unroll
        for (int m = 0; m < 4; ++m)
            a[m] = *(const short8*)(As + buf * 4096 +
                                    (wm * 64 + m * 16 + (lane & 15)) * 32 +
                                    (lane >> 4) * 8);
#pragma unroll
        for (int n = 0; n < 4; ++n)
            b[n] = *(const short8*)(Bs + buf * 4096 +
                                    (wn * 64 + n * 16 + (lane & 15)) * 32 +
                                    (lane >> 4) * 8);
#pragma unroll
        for (int m = 0; m < 4; ++m)
#pragma unroll
            for (int n = 0; n < 4; ++n)
                acc[m][n] = __builtin_amdgcn_mfma_f32_16x16x32_bf16(
                    a[m], b[n], acc[m][n], 0, 0, 0);
        __syncthreads();
        buf ^= 1;
    }

#pragma unroll
    for (int m = 0; m < 4; ++m)
#pragma unroll
        for (int n = 0; n < 4; ++n)
#pragma unroll
            for (int r = 0; r < 4; ++r) {
                int row = rowA0 + wm * 64 + m * 16 + (lane >> 4) * 4 + r;
                int col = rowB0 + wn * 64 + n * 16 + (lane & 15);
                out[(size_t)row * 768 + col] = acc[m][n][r] + bp[col];
            }
}

// ---------------------------------------------------------------- attention
__global__ __launch_bounds__(256, 2) void k_attn(const u16* __restrict__ Qb,
                                                 const u16* __restrict__ Kb,
                                                 const u16* __restrict__ VTg,
                                                 u16* __restrict__ xattn) {
    __shared__ __align__(16) u16 Ks[2][4096];
    __shared__ __align__(16) u16 Vs[2][4096];
    int b8 = blockIdx.x;
    int sw = (b8 & 7) * 96 + (b8 >> 3);  // XCD clustering: 12 heads per XCD
    int bh = sw >> 3, qblk = sw & 7;
    int bb = bh / 12, hh = bh % 12;
    int tid = threadIdx.x, lane = tid & 63, w = tid >> 6;
    int g = lane >> 4, c = lane & 15;
    const char* Kp = (const char*)(Kb + ((size_t)bh << 16));
    const char* Vp = (const char*)(VTg + ((size_t)bh << 16));
    const u16* Qp = Qb + ((size_t)bh << 16);
    int q0 = qblk * 128 + w * 32;

    short8 qf[2][2];
#pragma unroll
    for (int qb = 0; qb < 2; ++qb)
#pragma unroll
        for (int ks = 0; ks < 2; ++ks)
            qf[qb][ks] = *(const short8*)(Qp + (size_t)(q0 + qb * 16 + c) * 64 +
                                          ks * 32 + g * 8);

    f32x4 o[2][4];
#pragma unroll
    for (int qb = 0; qb < 2; ++qb)
#pragma unroll
        for (int n = 0; n < 4; ++n) o[qb][n] = (f32x4){0.f, 0.f, 0.f, 0.f};
    float lsum[2] = {0.f, 0.f};

    int kgo[2], vgo[2], ldo[2];
#pragma unroll
    for (int h = 0; h < 2; ++h) {
        int idx = w * 64 + lane + h * 256;
        int row = idx >> 3;
        int colb = ((idx & 7) * 16) ^ ((row & 7) << 4);
        kgo[h] = row * 128 + colb;
        vgo[h] = row * 2048 + colb;
        ldo[h] = (w * 64 + h * 256) * 16;
    }

    auto stage = [&](int bi, int t) {
#pragma unroll
        for (int h = 0; h < 2; ++h) {
            g2l16(Kp + (size_t)t * 8192 + kgo[h], (char*)&Ks[bi][0] + ldo[h]);
            g2l16(Vp + (size_t)t * 128 + vgo[h], (char*)&Vs[bi][0] + ldo[h]);
        }
    };

    stage(0, 0);
    __syncthreads();
    int buf = 0;
    int cs = (c & 7) << 4;
    for (int t = 0; t < 16; ++t) {
        if (t < 15) stage(buf ^ 1, t + 1);
        const char* Kbase = (const char*)&Ks[buf][0];
        const char* Vbase = (const char*)&Vs[buf][0];
        short8 kf[4][2], vf[4][2];
#pragma unroll
        for (int m = 0; m < 4; ++m) {
            int rowb = (m * 16 + c) * 128;
#pragma unroll
            for (int ks = 0; ks < 2; ++ks)
                kf[m][ks] = *(const short8*)(Kbase + rowb +
                                             ((g * 16 + ks * 64) ^ cs));
        }
#pragma unroll
        for (int n = 0; n < 4; ++n) {
            int rowb = (n * 16 + c) * 128;
#pragma unroll
            for (int a = 0; a < 2; ++a)
                vf[n][a] = *(const short8*)(Vbase + rowb +
                                            ((a * 64 + g * 16) ^ cs));
        }
#pragma unroll
        for (int qb = 0; qb < 2; ++qb) {
            f32x4 s[4];
            __builtin_amdgcn_s_setprio(1);
#pragma unroll
            for (int m = 0; m < 4; ++m) {
                s[m] = __builtin_amdgcn_mfma_f32_16x16x32_bf16(
                    kf[m][0], qf[qb][0], (f32x4){0.f, 0.f, 0.f, 0.f}, 0, 0, 0);
                s[m] = __builtin_amdgcn_mfma_f32_16x16x32_bf16(
                    kf[m][1], qf[qb][1], s[m], 0, 0, 0);
            }
            __builtin_amdgcn_s_setprio(0);
            u32 P2[4][2];
            float ls = 0.f;
#pragma unroll
            for (int m = 0; m < 4; ++m) {
#pragma unroll
                for (int r = 0; r < 4; ++r) {
                    s[m][r] = exp2f(s[m][r]);
                    ls += s[m][r];
                }
                P2[m][0] = pk2(s[m][0], s[m][1]);
                P2[m][1] = pk2(s[m][2], s[m][3]);
            }
            lsum[qb] += ls;
#pragma unroll
            for (int a = 0; a < 2; ++a) {
                union { u32 u[4]; short8 s8; } pu;
                pu.u[0] = P2[0][a]; pu.u[1] = P2[1][a];
                pu.u[2] = P2[2][a]; pu.u[3] = P2[3][a];
                __builtin_amdgcn_s_setprio(1);
#pragma unroll
                for (int n = 0; n < 4; ++n)
                    o[qb][n] = __builtin_amdgcn_mfma_f32_16x16x32_bf16(
                        pu.s8, vf[n][a], o[qb][n], 0, 0, 0);
                __builtin_amdgcn_s_setprio(0);
            }
        }
        __syncthreads();
        buf ^= 1;
    }

#pragma unroll
    for (int qb = 0; qb < 2; ++qb) {
        float L = lsum[qb];
        L += __shfl_xor(L, 16);
        L += __shfl_xor(L, 32);
        float rl[4];
#pragma unroll
        for (int r = 0; r < 4; ++r) rl[r] = 1.0f / __shfl(L, g * 4 + r);
#pragma unroll
        for (int n = 0; n < 4; ++n)
#pragma unroll
            for (int r = 0; r < 4; ++r) {
                int q = q0 + qb * 16 + 4 * g + r;
                int d = n * 16 + c;
                xattn[(size_t)(bb * 1024 + q) * 768 + hh * 64 + d] =
                    f2bf(o[qb][n][r] * rl[r]);
            }
    }
}

// ---------------------------------------------------------------- combine
__global__ __launch_bounds__(256) void k_combine(
    const u16* __restrict__ xattn, const u16* __restrict__ vlin,
    const float* __restrict__ glf, const float* __restrict__ ghf,
    const float* __restrict__ lfg, const float* __restrict__ hfg,
    u16* __restrict__ xfinal) {
    int i = blockIdx.x * 256 + threadIdx.x;
    size_t base = (size_t)i * 8;
    int c = (int)(base % 768);
    int t = (int)(base / 768);
    int h = c >> 6;
    float a_lf = glf[(size_t)t * 12 + h];
    float a_hf = ghf[(size_t)t * 12 + h];
    short8 xa8 = *((const short8*)xattn + i);
    short8 vl8 = *((const short8*)vlin + i);
    float4 lg0 = *(const float4*)(lfg + c);
    float4 lg1 = *(const float4*)(lfg + c + 4);
    float4 hg0 = *(const float4*)(hfg + c);
    float4 hg1 = *(const float4*)(hfg + c + 4);
    float lg[8] = {lg0.x, lg0.y, lg0.z, lg0.w, lg1.x, lg1.y, lg1.z, lg1.w};
    float hg[8] = {hg0.x, hg0.y, hg0.z, hg0.w, hg1.x, hg1.y, hg1.z, hg1.w};
    short8 o;
#pragma unroll
    for (int j = 0; j < 8; ++j) {
        float xa = bf2f((u16)xa8[j]);
        float v = bf2f((u16)vl8[j]);
        float val = xa + xa * a_lf * lg[j] + a_hf * (v - xa) * hg[j];
        o[j] = f2bf(val);
    }
    *((short8*)xfinal + i) = o;
}

// ---------------------------------------------------------------- launch
extern "C" void kernel_launch(void* const* d_in, const int* in_sizes, int n_in,
                              void* d_out, int out_size, void* d_ws,
                              size_t ws_size, hipStream_t stream) {
    const float* q_in = (const float*)d_in[0];
    const float* kv_in = (const float*)d_in[1];
    const float* Wq = (const float*)d_in[2];
    const float* Wk = (const float*)d_in[3];
    const float* Wv = (const float*)d_in[4];
    const float* Wp = (const float*)d_in[5];
    const float* bp = (const float*)d_in[6];
    const float* Wdy2 = (const float*)d_in[7];
    const float* bdy2 = (const float*)d_in[8];
    const float* Wdy = (const float*)d_in[9];
    const float* bdy = (const float*)d_in[10];
    const float* lfg = (const float*)d_in[11];
    const float* hfg = (const float*)d_in[12];
    const float* st_s = (const float*)d_in[13];
    const float* st_b = (const float*)d_in[14];
    float* out = (float*)d_out;

    char* ws = (char*)d_ws;
    const size_t MC2 = (size_t)8192 * 768 * 2;
    const size_t WB = (size_t)768 * 768 * 2;
    u16* qbf = (u16*)(ws);
    u16* kvbf = (u16*)(ws + MC2);
    u16* Wqb = (u16*)(ws + 2 * MC2);
    u16* Wkb = (u16*)(ws + 2 * MC2 + WB);
    u16* Wvb = (u16*)(ws + 2 * MC2 + 2 * WB);
    u16* Wpb = (u16*)(ws + 2 * MC2 + 3 * WB);
    u16* Qb = (u16*)(ws + 2 * MC2 + 4 * WB);
    u16* Kb = (u16*)(ws + 3 * MC2 + 4 * WB);
    u16* VTg = (u16*)(ws + 4 * MC2 + 4 * WB);
    u16* vlin = (u16*)(ws + 5 * MC2 + 4 * WB);
    float* glf = (float*)(ws + 6 * MC2 + 4 * WB);
    float* ghf = (float*)(ws + 6 * MC2 + 4 * WB + (size_t)8192 * 12 * 4);
    u16* xattn = kvbf;
    u16* xfinal = qbf;

    k_cvt2<<<dim3(3072, 2), 256, 0, stream>>>(q_in, kv_in, qbf, kvbf, 786432);
    k_cvt4<<<dim3(288, 4), 256, 0, stream>>>(Wq, Wk, Wv, Wp, Wqb, Wkb, Wvb,
                                             Wpb, 73728);
    k_gates_mm<<<128, 256, 0, stream>>>(q_in, Wdy2, bdy2, Wdy, bdy, st_s,
                                        st_b, glf, ghf);
    k_gemm_qkv<<<768, 256, 0, stream>>>(qbf, kvbf, Wqb, Wkb, Wvb, Qb, Kb, VTg,
                                        vlin);
    k_attn<<<768, 256, 0, stream>>>(Qb, Kb, VTg, xattn);
    k_combine<<<3072, 256, 0, stream>>>(xattn, vlin, glf, ghf, lfg, hfg,
                                        xfinal);
    k_gemm_out<<<384, 256, 0, stream>>>(xfinal, Wpb, bp, out);
}

// Round 4
// 157.624 us; speedup vs baseline: 1.9011x; 1.2372x over previous
//
#include <hip/hip_runtime.h>
#include <hip/hip_bf16.h>
#include <stdint.h>

typedef unsigned short u16;
typedef unsigned int u32;
typedef unsigned long long u64;
typedef __attribute__((ext_vector_type(8))) short short8;
typedef __attribute__((ext_vector_type(4))) float f32x4;

#define LOG2E 1.44269504f

static __device__ __forceinline__ u16 f2bf(float f) {
    u32 x = __float_as_uint(f);
    u32 r = (x + 0x7FFFu + ((x >> 16) & 1u)) >> 16;
    return (u16)r;
}
static __device__ __forceinline__ float bf2f(u16 u) {
    return __uint_as_float(((u32)u) << 16);
}
static __device__ __forceinline__ u32 pk2(float lo, float hi) {
    __hip_bfloat162 t = __float22bfloat162_rn(float2{lo, hi});
    union { __hip_bfloat162 b; u32 u; } cv;
    cv.b = t;
    return cv.u;
}

static __device__ __forceinline__ void g2l16(const void* g, void* l) {
    __builtin_amdgcn_global_load_lds((const __attribute__((address_space(1))) void*)g,
                                     (__attribute__((address_space(3))) void*)l, 16, 0, 0);
}

// ---------------------------------------------------------------- convert (all tensors, one launch)
__global__ __launch_bounds__(256) void k_cvt_all(
    const float* __restrict__ q_in, const float* __restrict__ kv_in,
    const float* __restrict__ Wq, const float* __restrict__ Wk,
    const float* __restrict__ Wv, const float* __restrict__ Wp,
    const float* __restrict__ Wdy2, const float* __restrict__ Wdy,
    u16* __restrict__ qbf, u16* __restrict__ kvbf, u16* __restrict__ Wqb,
    u16* __restrict__ Wkb, u16* __restrict__ Wvb, u16* __restrict__ Wpb,
    u16* __restrict__ wgb) {
    int i = blockIdx.x * 256 + threadIdx.x;
    const float* src;
    u16* dst;
    int so, dofs;
    if (i < 786432) { src = q_in; dst = qbf; so = i; dofs = i; }
    else if (i < 1572864) { src = kv_in; dst = kvbf; so = i - 786432; dofs = so; }
    else if (i < 1646592) { src = Wq; dst = Wqb; so = i - 1572864; dofs = so; }
    else if (i < 1720320) { src = Wk; dst = Wkb; so = i - 1646592; dofs = so; }
    else if (i < 1794048) { src = Wv; dst = Wvb; so = i - 1720320; dofs = so; }
    else if (i < 1867776) { src = Wp; dst = Wpb; so = i - 1794048; dofs = so; }
    else if (i < 1870080) {
        int e = i - 1867776;
        dst = wgb; dofs = e;
        if (e < 1152) { src = Wdy2; so = e; }
        else { src = Wdy; so = e - 1152; }
    } else return;
    const float4* p = (const float4*)src + (size_t)so * 2;
    float4 a = p[0], b = p[1];
    short8 o;
    o[0] = f2bf(a.x); o[1] = f2bf(a.y); o[2] = f2bf(a.z); o[3] = f2bf(a.w);
    o[4] = f2bf(b.x); o[5] = f2bf(b.y); o[6] = f2bf(b.z); o[7] = f2bf(b.w);
    *((short8*)dst + dofs) = o;
}

// ---------------------------------------------------------------- gates (1-wave blocks, no LDS, no barriers)
// feat = StarReLU(q_in) computed in registers from bf16 qbf; (16 rows) x (768) @ wgb^T (24 outs)
__global__ __launch_bounds__(64) void k_gates(
    const u16* __restrict__ qbf, const u16* __restrict__ wgb,
    const float* __restrict__ bdy2, const float* __restrict__ bdy,
    const float* __restrict__ star_s, const float* __restrict__ star_b,
    float* __restrict__ glf, float* __restrict__ ghf) {
    int lane = threadIdx.x;
    int g = lane >> 4, c = lane & 15;
    int row0 = blockIdx.x * 16;
    float ss = star_s[0], sb = star_b[0];
    f32x4 acc[2];
    acc[0] = (f32x4){0.f, 0.f, 0.f, 0.f};
    acc[1] = (f32x4){0.f, 0.f, 0.f, 0.f};
    for (int t = 0; t < 24; ++t) {
        int k0 = t * 32;
        short8 x8 = *(const short8*)(qbf + (size_t)(row0 + c) * 768 + k0 + g * 8);
        float f[8];
#pragma unroll
        for (int j = 0; j < 8; ++j) {
            float x = fmaxf(bf2f((u16)x8[j]), 0.f);
            f[j] = ss * x * x + sb;
        }
        union { u32 u[4]; short8 s8; } au;
#pragma unroll
        for (int j = 0; j < 4; ++j) au.u[j] = pk2(f[2 * j], f[2 * j + 1]);
        short8 b0 = *(const short8*)(wgb + (size_t)c * 768 + k0 + g * 8);
        short8 b1 = (short8){0, 0, 0, 0, 0, 0, 0, 0};
        if (c < 8)
            b1 = *(const short8*)(wgb + (size_t)(16 + c) * 768 + k0 + g * 8);
        acc[0] = __builtin_amdgcn_mfma_f32_16x16x32_bf16(au.s8, b0, acc[0], 0, 0, 0);
        acc[1] = __builtin_amdgcn_mfma_f32_16x16x32_bf16(au.s8, b1, acc[1], 0, 0, 0);
    }
#pragma unroll
    for (int n = 0; n < 2; ++n)
#pragma unroll
        for (int r = 0; r < 4; ++r) {
            int token = row0 + g * 4 + r;
            int o = n * 16 + c;
            float v = acc[n][r];
            if (o < 12) {
                glf[(size_t)token * 12 + o] = tanhf(v + bdy2[o]);
            } else if (o < 24) {
                float x = v + bdy[o - 12];
                float sp = (x > 15.f) ? x : log1pf(expf(x));
                float d2 = sp * sp;
                ghf[(size_t)token * 12 + (o - 12)] = 2.f * d2 / (d2 + 0.3678f);
            }
        }
}

// ---------------------------------------------------------------- GEMM core (swizzled LDS, 128x128, BK=32)
__device__ __forceinline__ void gemm_core(const u16* __restrict__ A,
                                          const u16* __restrict__ W, u16* As,
                                          u16* Bs, int rowA0, int rowB0,
                                          int lane, int w, int wm, int wn,
                                          f32x4 acc[4][4]) {
    int g = lane >> 4, c = lane & 15;
#pragma unroll
    for (int m = 0; m < 4; ++m)
#pragma unroll
        for (int n = 0; n < 4; ++n) acc[m][n] = (f32x4){0.f, 0.f, 0.f, 0.f};

    // LDS layout: [row 0..127][slot 0..3] of 16B, slot swizzled by row&3.
    // global_load_lds dest is linear; inverse swizzle applied on SOURCE.
    auto stage = [&](int buf, int k0) {
#pragma unroll
        for (int j = 0; j < 2; ++j) {
            int idx = w * 128 + j * 64 + lane;
            int row = idx >> 2;
            int sl = (idx & 3) ^ (row & 3);
            size_t goA = (size_t)(rowA0 + row) * 768 + k0 + sl * 8;
            size_t goB = (size_t)(rowB0 + row) * 768 + k0 + sl * 8;
            int lo = (w * 128 + j * 64) * 8;
            g2l16(A + goA, As + buf * 4096 + lo);
            g2l16(W + goB, Bs + buf * 4096 + lo);
        }
    };

    stage(0, 0);
    __syncthreads();
    int buf = 0;
    for (int t = 0; t < 24; ++t) {
        if (t < 23) stage(buf ^ 1, (t + 1) * 32);
        short8 a[4], b[4];
#pragma unroll
        for (int m = 0; m < 4; ++m)
            a[m] = *(const short8*)(As + buf * 4096 +
                                    (wm * 64 + m * 16 + c) * 32 +
                                    (g ^ (c & 3)) * 8);
#pragma unroll
        for (int n = 0; n < 4; ++n)
            b[n] = *(const short8*)(Bs + buf * 4096 +
                                    (wn * 64 + n * 16 + c) * 32 +
                                    (g ^ (c & 3)) * 8);
#pragma unroll
        for (int m = 0; m < 4; ++m)
#pragma unroll
            for (int n = 0; n < 4; ++n)
                acc[m][n] = __builtin_amdgcn_mfma_f32_16x16x32_bf16(
                    a[m], b[n], acc[m][n], 0, 0, 0);
        __syncthreads();
        buf ^= 1;
    }
}

// ---------------------------------------------------------------- QKV GEMM (uniform blocks)
__global__ __launch_bounds__(256, 2) void k_gemm_qkv(
    const u16* __restrict__ qbf, const u16* __restrict__ kvbf,
    const u16* __restrict__ Wqb, const u16* __restrict__ Wkb,
    const u16* __restrict__ Wvb, u16* __restrict__ Qb, u16* __restrict__ Kb,
    u16* __restrict__ VTg, u16* __restrict__ vlin) {
    __shared__ __align__(16) u16 smem[16384];
    u16* As = smem;
    u16* Bs = smem + 8192;
    int bid = blockIdx.x;
    // XCD-chunked: 144 logical blocks per XCD = 8 row panels x 18 tiles
    // (6 Q + 6 K + 6 V), panel-major so A panels stay hot in XCD L2.
    int logical = (bid & 7) * 144 + (bid >> 3);
    int panel = logical / 18, sub = logical % 18;
    int type = sub / 6, tn = sub % 6;
    int tid = threadIdx.x, lane = tid & 63, w = tid >> 6;
    int g = lane >> 4, c = lane & 15;
    int wm = w >> 1, wn = w & 1;
    int rowA0 = panel * 128, rowB0 = tn * 128;
    const u16* A = (type == 0) ? qbf : kvbf;
    const u16* W = (type == 0) ? Wqb : (type == 1) ? Wkb : Wvb;

    f32x4 acc[4][4];
    gemm_core(A, W, As, Bs, rowA0, rowB0, lane, w, wm, wn, acc);

    if (type == 0) {
        const float scl = 0.125f * LOG2E;
#pragma unroll
        for (int m = 0; m < 4; ++m)
#pragma unroll
            for (int n = 0; n < 4; ++n)
#pragma unroll
                for (int r = 0; r < 4; ++r) {
                    int row = rowA0 + wm * 64 + m * 16 + g * 4 + r;
                    int col = rowB0 + wn * 64 + n * 16 + c;
                    int bb = row >> 10, nn = row & 1023, hh = col >> 6,
                        dd = col & 63;
                    Qb[((size_t)(bb * 12 + hh) << 16) + (nn << 6) + dd] =
                        f2bf(acc[m][n][r] * scl);
                }
    } else if (type == 1) {
#pragma unroll
        for (int m = 0; m < 4; ++m)
#pragma unroll
            for (int n = 0; n < 4; ++n)
#pragma unroll
                for (int r = 0; r < 4; ++r) {
                    int row = rowA0 + wm * 64 + m * 16 + g * 4 + r;
                    int col = rowB0 + wn * 64 + n * 16 + c;
                    int bb = row >> 10, nn = row & 1023, hh = col >> 6,
                        dd = col & 63;
                    Kb[((size_t)(bb * 12 + hh) << 16) + (nn << 6) + dd] =
                        f2bf(acc[m][n][r]);
                }
    } else {
#pragma unroll
        for (int m = 0; m < 4; ++m)
#pragma unroll
            for (int n = 0; n < 4; ++n)
#pragma unroll
                for (int r = 0; r < 4; ++r) {
                    int row = rowA0 + wm * 64 + m * 16 + g * 4 + r;
                    int col = rowB0 + wn * 64 + n * 16 + c;
                    vlin[(size_t)row * 768 + col] = f2bf(acc[m][n][r]);
                }
        __syncthreads();
        // transpose V tile (128 tokens x 128 douts) through LDS
#pragma unroll
        for (int m = 0; m < 4; ++m)
#pragma unroll
            for (int n = 0; n < 4; ++n)
#pragma unroll
                for (int r = 0; r < 4; ++r) {
                    int rl = wm * 64 + m * 16 + g * 4 + r;
                    int cl = wn * 64 + n * 16 + c;
                    smem[cl * 128 + rl] = f2bf(acc[m][n][r]);
                }
        __syncthreads();
        int bb = rowA0 >> 10, nn0 = rowA0 & 1023;
        // write V^T with per-64-token k-permutation rho (PV fragment-ready)
#pragma unroll
        for (int j = 0; j < 8; ++j) {
            int idx = j * 256 + tid;
            int rT = idx >> 4, cc = idx & 15;
            int dout = rowB0 + rT, hh = dout >> 6, dd = dout & 63;
            const u16* srow = smem + rT * 128 + cc * 8;
            size_t robase = ((size_t)(bb * 12 + hh) * 64 + dd) * 1024;
#pragma unroll
            for (int e2 = 0; e2 < 4; ++e2) {
                int n0 = nn0 + cc * 8 + 2 * e2;
                int t6 = n0 & 63;
                int pos = (((t6 >> 1) & 1) << 5) | (((t6 >> 2) & 3) << 3) |
                          (((t6 >> 4) & 3) << 1) | (t6 & 1);
                u32 val = (u32)srow[2 * e2] | ((u32)srow[2 * e2 + 1] << 16);
                *(u32*)(VTg + robase + (n0 & ~63) + pos) = val;
            }
        }
    }
}

// ---------------------------------------------------------------- out GEMM
__global__ __launch_bounds__(256, 2) void k_gemm_out(
    const u16* __restrict__ xf, const u16* __restrict__ Wpb,
    const float* __restrict__ bp, float* __restrict__ out) {
    __shared__ __align__(16) u16 smem[16384];
    u16* As = smem;
    u16* Bs = smem + 8192;
    int bid = blockIdx.x;
    int logical = (bid & 7) * 48 + (bid >> 3);
    int c48 = logical % 48;
    int tm = (logical / 48) * 8 + c48 / 6, tn = c48 % 6;
    int tid = threadIdx.x, lane = tid & 63, w = tid >> 6;
    int wm = w >> 1, wn = w & 1;
    int rowA0 = tm * 128, rowB0 = tn * 128;

    f32x4 acc[4][4];
    gemm_core(xf, Wpb, As, Bs, rowA0, rowB0, lane, w, wm, wn, acc);

#pragma unroll
    for (int m = 0; m < 4; ++m)
#pragma unroll
        for (int n = 0; n < 4; ++n)
#pragma unroll
            for (int r = 0; r < 4; ++r) {
                int row = rowA0 + wm * 64 + m * 16 + (lane >> 4) * 4 + r;
                int col = rowB0 + wn * 64 + n * 16 + (lane & 15);
                out[(size_t)row * 768 + col] = acc[m][n][r] + bp[col];
            }
}

// ---------------------------------------------------------------- attention (+fused combine)
__global__ __launch_bounds__(256, 2) void k_attn(
    const u16* __restrict__ Qb, const u16* __restrict__ Kb,
    const u16* __restrict__ VTg, const u16* __restrict__ vlin,
    const float* __restrict__ glf, const float* __restrict__ ghf,
    const float* __restrict__ lfg, const float* __restrict__ hfg,
    u16* __restrict__ xfinal) {
    __shared__ __align__(16) u16 Ks[2][4096];
    __shared__ __align__(16) u16 Vs[2][4096];
    int b8 = blockIdx.x;
    int sw = (b8 & 7) * 96 + (b8 >> 3);  // XCD clustering: 12 heads per XCD
    int bh = sw >> 3, qblk = sw & 7;
    int bb = bh / 12, hh = bh % 12;
    int tid = threadIdx.x, lane = tid & 63, w = tid >> 6;
    int g = lane >> 4, c = lane & 15;
    const char* Kp = (const char*)(Kb + ((size_t)bh << 16));
    const char* Vp = (const char*)(VTg + ((size_t)bh << 16));
    const u16* Qp = Qb + ((size_t)bh << 16);
    int q0 = qblk * 128 + w * 32;

    short8 qf[2][2];
#pragma unroll
    for (int qb = 0; qb < 2; ++qb)
#pragma unroll
        for (int ks = 0; ks < 2; ++ks)
            qf[qb][ks] = *(const short8*)(Qp + (size_t)(q0 + qb * 16 + c) * 64 +
                                          ks * 32 + g * 8);

    f32x4 o[2][4];
#pragma unroll
    for (int qb = 0; qb < 2; ++qb)
#pragma unroll
        for (int n = 0; n < 4; ++n) o[qb][n] = (f32x4){0.f, 0.f, 0.f, 0.f};
    float lsum[2] = {0.f, 0.f};

    int kgo[2], vgo[2], ldo[2];
#pragma unroll
    for (int h = 0; h < 2; ++h) {
        int idx = w * 64 + lane + h * 256;
        int row = idx >> 3;
        int colb = ((idx & 7) * 16) ^ ((row & 7) << 4);
        kgo[h] = row * 128 + colb;
        vgo[h] = row * 2048 + colb;
        ldo[h] = (w * 64 + h * 256) * 16;
    }

    auto stage = [&](int bi, int t) {
#pragma unroll
        for (int h = 0; h < 2; ++h) {
            g2l16(Kp + (size_t)t * 8192 + kgo[h], (char*)&Ks[bi][0] + ldo[h]);
            g2l16(Vp + (size_t)t * 128 + vgo[h], (char*)&Vs[bi][0] + ldo[h]);
        }
    };

    stage(0, 0);
    __syncthreads();
    int buf = 0;
    int cs = (c & 7) << 4;
    for (int t = 0; t < 16; ++t) {
        if (t < 15) stage(buf ^ 1, t + 1);
        const char* Kbase = (const char*)&Ks[buf][0];
        const char* Vbase = (const char*)&Vs[buf][0];
        short8 kf[4][2], vf[4][2];
#pragma unroll
        for (int m = 0; m < 4; ++m) {
            int rowb = (m * 16 + c) * 128;
#pragma unroll
            for (int ks = 0; ks < 2; ++ks)
                kf[m][ks] = *(const short8*)(Kbase + rowb +
                                             ((g * 16 + ks * 64) ^ cs));
        }
#pragma unroll
        for (int n = 0; n < 4; ++n) {
            int rowb = (n * 16 + c) * 128;
#pragma unroll
            for (int a = 0; a < 2; ++a)
                vf[n][a] = *(const short8*)(Vbase + rowb +
                                            ((a * 64 + g * 16) ^ cs));
        }
#pragma unroll
        for (int qb = 0; qb < 2; ++qb) {
            f32x4 s[4];
            __builtin_amdgcn_s_setprio(1);
#pragma unroll
            for (int m = 0; m < 4; ++m) {
                s[m] = __builtin_amdgcn_mfma_f32_16x16x32_bf16(
                    kf[m][0], qf[qb][0], (f32x4){0.f, 0.f, 0.f, 0.f}, 0, 0, 0);
                s[m] = __builtin_amdgcn_mfma_f32_16x16x32_bf16(
                    kf[m][1], qf[qb][1], s[m], 0, 0, 0);
            }
            __builtin_amdgcn_s_setprio(0);
            u32 P2[4][2];
            float ls = 0.f;
#pragma unroll
            for (int m = 0; m < 4; ++m) {
#pragma unroll
                for (int r = 0; r < 4; ++r) {
                    s[m][r] = exp2f(s[m][r]);
                    ls += s[m][r];
                }
                P2[m][0] = pk2(s[m][0], s[m][1]);
                P2[m][1] = pk2(s[m][2], s[m][3]);
            }
            lsum[qb] += ls;
#pragma unroll
            for (int a = 0; a < 2; ++a) {
                union { u32 u[4]; short8 s8; } pu;
                pu.u[0] = P2[0][a]; pu.u[1] = P2[1][a];
                pu.u[2] = P2[2][a]; pu.u[3] = P2[3][a];
                __builtin_amdgcn_s_setprio(1);
#pragma unroll
                for (int n = 0; n < 4; ++n)
                    o[qb][n] = __builtin_amdgcn_mfma_f32_16x16x32_bf16(
                        pu.s8, vf[n][a], o[qb][n], 0, 0, 0);
                __builtin_amdgcn_s_setprio(0);
            }
        }
        __syncthreads();
        buf ^= 1;
    }

    // fused combine epilogue: out = xa + xa*a_lf*lfg + a_hf*(v - xa)*hfg
#pragma unroll
    for (int qb = 0; qb < 2; ++qb) {
        float L = lsum[qb];
        L += __shfl_xor(L, 16);
        L += __shfl_xor(L, 32);
        float rl[4], alf[4], ahf[4];
        size_t trow[4];
#pragma unroll
        for (int r = 0; r < 4; ++r) {
            rl[r] = 1.0f / __shfl(L, g * 4 + r);
            int q = q0 + qb * 16 + 4 * g + r;
            trow[r] = (size_t)(bb * 1024 + q);
            alf[r] = glf[trow[r] * 12 + hh];
            ahf[r] = ghf[trow[r] * 12 + hh];
        }
#pragma unroll
        for (int n = 0; n < 4; ++n) {
            int col = hh * 64 + n * 16 + c;
            float lf = lfg[col], hf = hfg[col];
#pragma unroll
            for (int r = 0; r < 4; ++r) {
                float xa = o[qb][n][r] * rl[r];
                float v = bf2f(vlin[trow[r] * 768 + col]);
                float val = xa + xa * alf[r] * lf + ahf[r] * (v - xa) * hf;
                xfinal[trow[r] * 768 + col] = f2bf(val);
            }
        }
    }
}

// ---------------------------------------------------------------- launch
extern "C" void kernel_launch(void* const* d_in, const int* in_sizes, int n_in,
                              void* d_out, int out_size, void* d_ws,
                              size_t ws_size, hipStream_t stream) {
    const float* q_in = (const float*)d_in[0];
    const float* kv_in = (const float*)d_in[1];
    const float* Wq = (const float*)d_in[2];
    const float* Wk = (const float*)d_in[3];
    const float* Wv = (const float*)d_in[4];
    const float* Wp = (const float*)d_in[5];
    const float* bp = (const float*)d_in[6];
    const float* Wdy2 = (const float*)d_in[7];
    const float* bdy2 = (const float*)d_in[8];
    const float* Wdy = (const float*)d_in[9];
    const float* bdy = (const float*)d_in[10];
    const float* lfg = (const float*)d_in[11];
    const float* hfg = (const float*)d_in[12];
    const float* st_s = (const float*)d_in[13];
    const float* st_b = (const float*)d_in[14];
    float* out = (float*)d_out;

    char* ws = (char*)d_ws;
    const size_t MC2 = (size_t)8192 * 768 * 2;
    const size_t WB = (size_t)768 * 768 * 2;
    u16* qbf = (u16*)(ws);
    u16* kvbf = (u16*)(ws + MC2);
    u16* Wqb = (u16*)(ws + 2 * MC2);
    u16* Wkb = (u16*)(ws + 2 * MC2 + WB);
    u16* Wvb = (u16*)(ws + 2 * MC2 + 2 * WB);
    u16* Wpb = (u16*)(ws + 2 * MC2 + 3 * WB);
    u16* Qb = (u16*)(ws + 2 * MC2 + 4 * WB);
    u16* Kb = (u16*)(ws + 3 * MC2 + 4 * WB);
    u16* VTg = (u16*)(ws + 4 * MC2 + 4 * WB);
    u16* vlin = (u16*)(ws + 5 * MC2 + 4 * WB);
    float* glf = (float*)(ws + 6 * MC2 + 4 * WB);
    float* ghf = (float*)(ws + 6 * MC2 + 4 * WB + (size_t)8192 * 12 * 4);
    u16* wgb = (u16*)(ws + 6 * MC2 + 4 * WB + (size_t)8192 * 12 * 8);
    u16* xfinal = qbf;  // alias: qbf dead after qkv GEMM + gates

    k_cvt_all<<<7305, 256, 0, stream>>>(q_in, kv_in, Wq, Wk, Wv, Wp, Wdy2,
                                        Wdy, qbf, kvbf, Wqb, Wkb, Wvb, Wpb,
                                        wgb);
    k_gates<<<512, 64, 0, stream>>>(qbf, wgb, bdy2, bdy, st_s, st_b, glf, ghf);
    k_gemm_qkv<<<1152, 256, 0, stream>>>(qbf, kvbf, Wqb, Wkb, Wvb, Qb, Kb,
                                         VTg, vlin);
    k_attn<<<768, 256, 0, stream>>>(Qb, Kb, VTg, vlin, glf, ghf, lfg, hfg,
                                    xfinal);
    k_gemm_out<<<384, 256, 0, stream>>>(xfinal, Wpb, bp, out);
}